// Round 3
// baseline (113.465 us; speedup 1.0000x reference)
//
#include <hip/hip_runtime.h>

// ---------------------------------------------------------------------------
// LMU fused cell on MI355X (gfx950), bf16 MFMA.  Round 3: algebraic refactor.
//   new_h = sigmoid([x|h|m] @ [Wx|Wh|Wm@AT]^T + u*(Wm@BT)^T),  u = x ex + h eh + m em
//   new_m = m @ AT^T + u * BT^T
// Single K-chunked double-buffered GEMM (BM=64, BK=128, 7 chunks), A staged
// f32->bf16 in LDS (T14 split), u accumulated during staging in f32.
// Prologue: lmu_pack packs Wx|Wh + AT to bf16 B-layout and computes wu=Wm@BT;
//           lmu_wm2 computes Wm2=Wm@AT and writes it bf16-packed in place.
// ---------------------------------------------------------------------------

typedef __bf16 bf16;
typedef bf16  bf16x8 __attribute__((ext_vector_type(8)));
typedef float f32x4  __attribute__((ext_vector_type(4)));
typedef unsigned short u16;

#define BATCH 16384
#define BM 64
// ws layout (u16 units)
#define WPACK 0         // [896/8][512][8] = 458752 u16 (k>=640 region = Wm2)
#define ATPACK 458752   // [256/8][256][8] = 65536 u16
#define WUOFF 524288    // 512 f32 (1024 u16)
#define PACK_ITEMS 393728   // 327680 (Wx|Wh) + 65536 (atpack) + 512 (wu)

__device__ __forceinline__ u16 f2bf(float f) {
  unsigned u = __builtin_bit_cast(unsigned, f);
  u += 0x7FFFu + ((u >> 16) & 1u);   // RNE
  return (u16)(u >> 16);
}
__device__ __forceinline__ int swz(int row, int cb) {
  return cb ^ ((row & 7) << 4);
}

// ---------------- prologue 1: pack Wx|Wh, AT; compute wu = Wm@BT ----------
__global__ __launch_bounds__(256) void lmu_pack(
    const float* __restrict__ Wx, const float* __restrict__ Wh,
    const float* __restrict__ Wm, const float* __restrict__ AT,
    const float* __restrict__ BT, u16* __restrict__ ws) {
  int i = blockIdx.x * 256 + threadIdx.x;
  if (i < 327680) {                     // Wall^T[k][n], k<640
    int j = i & 7, rest = i >> 3;
    int n = rest & 511, kk = rest >> 9;
    int k = kk * 8 + j;
    float v = (k < 128) ? Wx[n * 128 + k] : Wh[n * 512 + (k - 128)];
    ws[WPACK + i] = f2bf(v);
  } else if (i < 393216) {              // AT^T packed: atpack[kk][d][j] = AT[d][kk*8+j]
    int t = i - 327680;
    int j = t & 7, rest = t >> 3;
    int d = rest & 255, kk = rest >> 8;
    ws[ATPACK + t] = f2bf(AT[d * 256 + kk * 8 + j]);
  } else if (i < PACK_ITEMS) {          // wu[n] = dot(Wm[n,:], BT)
    int n = i - 393216;
    float s = 0.f;
    for (int k = 0; k < 256; k += 4) {
      float4 wv = *(const float4*)(Wm + (size_t)n * 256 + k);
      float4 bv = *(const float4*)(BT + k);
      s += wv.x * bv.x + wv.y * bv.y + wv.z * bv.z + wv.w * bv.w;
    }
    ((float*)(ws + WUOFF))[n] = s;
  }
}

// ---------------- prologue 2: Wm2 = Wm @ AT, written bf16-packed -----------
// block: 16 Wm-rows x 64 d-cols; grid (32, 4); 256 threads.
__global__ __launch_bounds__(256) void lmu_wm2(
    const float* __restrict__ Wm, const float* __restrict__ AT,
    u16* __restrict__ ws) {
  __shared__ float wmt[16 * 256];
  const int t = threadIdx.x;
  const int nb = blockIdx.x * 16, db = blockIdx.y * 64;
#pragma unroll
  for (int it = 0; it < 4; ++it) {      // stage 16x256 f32 Wm tile
    int f = it * 256 + t;
    float4 v = *(const float4*)(Wm + (size_t)(nb + (f >> 6)) * 256 + (f & 63) * 4);
    *(float4*)(wmt + (f >> 6) * 256 + (f & 63) * 4) = v;
  }
  __syncthreads();
  const int d = db + (t & 63);
  const int nn = (t >> 6) * 4;
  float acc[4] = {0.f, 0.f, 0.f, 0.f};
  for (int k = 0; k < 256; ++k) {
    float atv = AT[(size_t)k * 256 + d];   // coalesced across lanes
#pragma unroll
    for (int i2 = 0; i2 < 4; ++i2) acc[i2] += wmt[(nn + i2) * 256 + k] * atv;
  }
  const int kk = 80 + (d >> 3), j = d & 7;
#pragma unroll
  for (int i2 = 0; i2 < 4; ++i2)
    ws[WPACK + ((size_t)kk * 512 + (nb + nn + i2)) * 8 + j] = f2bf(acc[i2]);
}

// ---------------- fused main kernel ----------------------------------------
// grid 256 x 512 threads. BM=64 rows/block. 8 waves = 2 (M) x 4 (N).
// LDS: double-buffered A chunk 64x128 bf16 (16KB each) + u[64] f32.
__global__ __launch_bounds__(512, 2) void lmu_fused(
    const float* __restrict__ x, const float* __restrict__ h,
    const float* __restrict__ m, const float* __restrict__ ex,
    const float* __restrict__ eh, const float* __restrict__ em,
    const float* __restrict__ BT, const u16* __restrict__ ws,
    float* __restrict__ out) {
  __shared__ __align__(16) char smem[2 * 16384 + 256];
  float* uL = (float*)(smem + 2 * 16384);

  const int tid  = threadIdx.x;
  const int lane = tid & 63;
  const int w    = tid >> 6;       // 0..7
  const int wr   = w >> 2;         // 0..1  (M tile of 32 rows)
  const int wc   = w & 3;          // 0..3  (N tile of 128 cols)
  const int lm   = lane & 15;
  const int kg   = lane >> 4;      // 0..3
  const int b0   = blockIdx.x * BM;
  const int r    = tid >> 3;       // staging row 0..63
  const int k0   = (tid & 7) * 16; // staging k-offset within chunk

  const u16* wpk = ws + WPACK;
  const u16* atp = ws + ATPACK;
  const float* wuf = (const float*)(ws + WUOFF);

  f32x4 acc[2][8];    // new_h tile: 2 Mfrag x 8 Nfrag
  f32x4 acc2[2][4];   // new_m tile: 2 Mfrag x 4 Nfrag
#pragma unroll
  for (int mt = 0; mt < 2; ++mt) {
#pragma unroll
    for (int ct = 0; ct < 8; ++ct) acc[mt][ct] = (f32x4){0.f, 0.f, 0.f, 0.f};
#pragma unroll
    for (int ct = 0; ct < 4; ++ct) acc2[mt][ct] = (f32x4){0.f, 0.f, 0.f, 0.f};
  }
  float ureg = 0.f;
  float4 av[4], ev[4];

  auto stage_load = [&](int c) {
    const float *ap, *ep;
    if (c == 0)      { ap = x + (size_t)(b0 + r) * 128 + k0;                 ep = ex + k0; }
    else if (c < 5)  { ap = h + (size_t)(b0 + r) * 512 + (c - 1) * 128 + k0; ep = eh + (c - 1) * 128 + k0; }
    else             { ap = m + (size_t)(b0 + r) * 256 + (c - 5) * 128 + k0; ep = em + (c - 5) * 128 + k0; }
#pragma unroll
    for (int i = 0; i < 4; ++i) { av[i] = *(const float4*)(ap + i * 4); ev[i] = *(const float4*)(ep + i * 4); }
  };
  auto stage_commit = [&](char* bufp) {
    float s = 0.f;
#pragma unroll
    for (int i = 0; i < 4; ++i)
      s += av[i].x * ev[i].x + av[i].y * ev[i].y + av[i].z * ev[i].z + av[i].w * ev[i].w;
    ureg += s;
    bf16x8 p0 = {(bf16)av[0].x, (bf16)av[0].y, (bf16)av[0].z, (bf16)av[0].w,
                 (bf16)av[1].x, (bf16)av[1].y, (bf16)av[1].z, (bf16)av[1].w};
    bf16x8 p1 = {(bf16)av[2].x, (bf16)av[2].y, (bf16)av[2].z, (bf16)av[2].w,
                 (bf16)av[3].x, (bf16)av[3].y, (bf16)av[3].z, (bf16)av[3].w};
    *(bf16x8*)(bufp + r * 256 + swz(r, k0 * 2))      = p0;
    *(bf16x8*)(bufp + r * 256 + swz(r, k0 * 2 + 16)) = p1;
  };
  auto mma_chunk = [&](const char* bufp, int c) {
#pragma unroll
    for (int ks = 0; ks < 4; ++ks) {
      bf16x8 a[2];
#pragma unroll
      for (int mt = 0; mt < 2; ++mt) {
        int row = wr * 32 + mt * 16 + lm;
        a[mt] = *(const bf16x8*)(bufp + row * 256 + swz(row, (ks * 32 + kg * 8) * 2));
      }
      const u16* wp = wpk + ((size_t)(c * 16 + ks * 4 + kg) * 512) * 8;
#pragma unroll
      for (int ct = 0; ct < 8; ++ct) {
        bf16x8 b = *(const bf16x8*)(wp + (wc * 128 + ct * 16 + lm) * 8);
#pragma unroll
        for (int mt = 0; mt < 2; ++mt)
          acc[mt][ct] = __builtin_amdgcn_mfma_f32_16x16x32_bf16(a[mt], b, acc[mt][ct], 0, 0, 0);
      }
      if (c >= 5) {                     // new_m side-GEMM on m chunks
        const u16* ap2 = atp + ((size_t)((c - 5) * 16 + ks * 4 + kg) * 256) * 8;
#pragma unroll
        for (int ct = 0; ct < 4; ++ct) {
          bf16x8 b = *(const bf16x8*)(ap2 + (wc * 64 + ct * 16 + lm) * 8);
#pragma unroll
          for (int mt = 0; mt < 2; ++mt)
            acc2[mt][ct] = __builtin_amdgcn_mfma_f32_16x16x32_bf16(a[mt], b, acc2[mt][ct], 0, 0, 0);
        }
      }
    }
  };

  // ---- pipelined K loop: 7 chunks, double-buffered ----
  stage_load(0);
  stage_commit(smem);
  __syncthreads();
#pragma unroll
  for (int c = 0; c < 7; ++c) {
    char* cur = smem + (c & 1) * 16384;
    char* nxt = smem + ((c + 1) & 1) * 16384;
    if (c < 6) stage_load(c + 1);      // issue early: HBM latency hides under MFMA
    mma_chunk(cur, c);
    if (c < 6) stage_commit(nxt);      // consume + write late (T14)
    __syncthreads();
  }

  // ---- u reduction (8 k-slots per row are 8 consecutive lanes) ----
  float s = ureg;
  s += __shfl_xor(s, 1);
  s += __shfl_xor(s, 2);
  s += __shfl_xor(s, 4);
  if ((tid & 7) == 0) uL[r] = s;
  __syncthreads();

  // ---- epilogue ----
  float wuv[8];
#pragma unroll
  for (int ct = 0; ct < 8; ++ct) wuv[ct] = wuf[wc * 128 + ct * 16 + lm];
  float btv[4];
#pragma unroll
  for (int ct = 0; ct < 4; ++ct) btv[ct] = BT[wc * 64 + ct * 16 + lm];
  float* outm = out + (size_t)BATCH * 512;
#pragma unroll
  for (int mt = 0; mt < 2; ++mt)
#pragma unroll
    for (int j = 0; j < 4; ++j) {
      int rl = wr * 32 + mt * 16 + kg * 4 + j;
      float uv = uL[rl];
      size_t grow = (size_t)(b0 + rl);
#pragma unroll
      for (int ct = 0; ct < 8; ++ct) {
        float v = acc[mt][ct][j] + uv * wuv[ct];
        out[grow * 512 + wc * 128 + ct * 16 + lm] = 1.0f / (1.0f + __expf(-v));
      }
#pragma unroll
      for (int ct = 0; ct < 4; ++ct)
        outm[grow * 256 + wc * 64 + ct * 16 + lm] = acc2[mt][ct][j] + uv * btv[ct];
    }
}

extern "C" void kernel_launch(void* const* d_in, const int* in_sizes, int n_in,
                              void* d_out, int out_size, void* d_ws, size_t ws_size,
                              hipStream_t stream) {
  const float* x  = (const float*)d_in[0];
  const float* h  = (const float*)d_in[1];
  const float* m  = (const float*)d_in[2];
  const float* Wx = (const float*)d_in[3];
  const float* Wh = (const float*)d_in[4];
  const float* Wm = (const float*)d_in[5];
  const float* ex = (const float*)d_in[6];
  const float* eh = (const float*)d_in[7];
  const float* em = (const float*)d_in[8];
  const float* AT = (const float*)d_in[9];
  const float* BT = (const float*)d_in[10];
  float* out = (float*)d_out;
  u16* ws = (u16*)d_ws;   // uses 1,050,624 bytes

  lmu_pack<<<(PACK_ITEMS + 255) / 256, 256, 0, stream>>>(Wx, Wh, Wm, AT, BT, ws);
  lmu_wm2<<<dim3(32, 4), 256, 0, stream>>>(Wm, AT, ws);
  lmu_fused<<<BATCH / BM, 512, 0, stream>>>(x, h, m, ex, eh, em, BT, ws, out);
}

// Round 4
// 67.920 us; speedup vs baseline: 1.6706x; 1.6706x over previous
//
#include <hip/hip_runtime.h>

// ---------------------------------------------------------------------------
// LMU fused cell on MI355X (gfx950).  Round 4: split prep + LDS-staged GEMM.
//   new_h = sigmoid([x|h|m] @ [Wx|Wh|Wm@AT]^T + u*(Wm@BT)^T)
//   new_m = m @ AT^T + u*BT^T          u = x ex + h eh + m em  (f32 exact)
// K1 (lmu_prep): f32 -> bf16 A-pack [16384][896] + u[16384] f32.
// K2 (lmu_gemm): BM=128 BN=128 BK=64x14, both operands via global_load_lds
//   into conflict-free packed LDS ([k/8][row][8]), 2-phase pipeline,
//   2 blocks/CU (80KB LDS), new_m as side-GEMM on chunks 10-13.
// ---------------------------------------------------------------------------

typedef __bf16 bf16;
typedef bf16  bf16x8 __attribute__((ext_vector_type(8)));
typedef float f32x4  __attribute__((ext_vector_type(4)));
typedef unsigned short u16;

#define BATCH 16384
// ws offsets (u16 units)
#define WPACK 0           // [896/8][512][8] = 458752 (k>=640 = Wm@AT)
#define ATPACK 458752     // [256/8][256][8] = 65536
#define WUOFF 524288      // 512 f32  (1024 u16)
#define UOFF  525312      // 16384 f32 (32768 u16)
#define APACK 558080      // 16384*896 u16
#define PACK_ITEMS 393728
// total ws use: (558080 + 14680064)*2 = 30,476,288 bytes

__device__ __forceinline__ u16 f2bf(float f) {
  unsigned u = __builtin_bit_cast(unsigned, f);
  u += 0x7FFFu + ((u >> 16) & 1u);   // RNE
  return (u16)(u >> 16);
}

__device__ __forceinline__ void gload16(const u16* g, u16* l) {
  __builtin_amdgcn_global_load_lds(
      (const __attribute__((address_space(1))) unsigned int*)g,
      (__attribute__((address_space(3))) unsigned int*)l, 16, 0, 0);
}

// ---------------- weight pack: Wx|Wh, AT, wu=Wm@BT (validated R3) ----------
__global__ __launch_bounds__(256) void lmu_pack(
    const float* __restrict__ Wx, const float* __restrict__ Wh,
    const float* __restrict__ Wm, const float* __restrict__ AT,
    const float* __restrict__ BT, u16* __restrict__ ws) {
  int i = blockIdx.x * 256 + threadIdx.x;
  if (i < 327680) {                     // Wall^T[k][n], k<640
    int j = i & 7, rest = i >> 3;
    int n = rest & 511, kk = rest >> 9;
    int k = kk * 8 + j;
    float v = (k < 128) ? Wx[n * 128 + k] : Wh[n * 512 + (k - 128)];
    ws[WPACK + i] = f2bf(v);
  } else if (i < 393216) {              // atpack[kk][d][j] = AT[d][kk*8+j]
    int t = i - 327680;
    int j = t & 7, rest = t >> 3;
    int d = rest & 255, kk = rest >> 8;
    ws[ATPACK + t] = f2bf(AT[d * 256 + kk * 8 + j]);
  } else if (i < PACK_ITEMS) {          // wu[n] = dot(Wm[n,:], BT)
    int n = i - 393216;
    float s = 0.f;
    for (int k = 0; k < 256; k += 4) {
      float4 wv = *(const float4*)(Wm + (size_t)n * 256 + k);
      float4 bv = *(const float4*)(BT + k);
      s += wv.x * bv.x + wv.y * bv.y + wv.z * bv.z + wv.w * bv.w;
    }
    ((float*)(ws + WUOFF))[n] = s;
  }
}

// ---------------- Wm2 = Wm @ AT, bf16-packed into wpack k>=640 (R3) --------
__global__ __launch_bounds__(256) void lmu_wm2(
    const float* __restrict__ Wm, const float* __restrict__ AT,
    u16* __restrict__ ws) {
  __shared__ float wmt[16 * 256];
  const int t = threadIdx.x;
  const int nb = blockIdx.x * 16, db = blockIdx.y * 64;
#pragma unroll
  for (int it = 0; it < 4; ++it) {
    int f = it * 256 + t;
    float4 v = *(const float4*)(Wm + (size_t)(nb + (f >> 6)) * 256 + (f & 63) * 4);
    *(float4*)(wmt + (f >> 6) * 256 + (f & 63) * 4) = v;
  }
  __syncthreads();
  const int d = db + (t & 63);
  const int nn = (t >> 6) * 4;
  float acc[4] = {0.f, 0.f, 0.f, 0.f};
  for (int k = 0; k < 256; ++k) {
    float atv = AT[(size_t)k * 256 + d];
#pragma unroll
    for (int i2 = 0; i2 < 4; ++i2) acc[i2] += wmt[(nn + i2) * 256 + k] * atv;
  }
  const int kk = 80 + (d >> 3), j = d & 7;
#pragma unroll
  for (int i2 = 0; i2 < 4; ++i2)
    ws[WPACK + ((size_t)kk * 512 + (nb + nn + i2)) * 8 + j] = f2bf(acc[i2]);
}

// ---------------- K1: A-pack bf16 + u (f32 exact) ---------------------------
// wave per row, lane reads cols lane+64j (coalesced), 4 rows/wave grid-stride.
__global__ __launch_bounds__(256) void lmu_prep(
    const float* __restrict__ x, const float* __restrict__ h,
    const float* __restrict__ m, const float* __restrict__ ex,
    const float* __restrict__ eh, const float* __restrict__ em,
    u16* __restrict__ ws) {
  const int lane = threadIdx.x & 63;
  const int wv = threadIdx.x >> 6;
  float* uout = (float*)(ws + UOFF);
  u16* apack = ws + APACK;
  for (int row = blockIdx.x * 4 + wv; row < BATCH; row += gridDim.x * 4) {
    float s = 0.f;
#pragma unroll
    for (int j = 0; j < 14; ++j) {
      int col = j * 64 + lane;
      float a, e;
      if (j < 2)       { a = x[(size_t)row * 128 + col];         e = ex[col]; }
      else if (j < 10) { a = h[(size_t)row * 512 + (col - 128)]; e = eh[col - 128]; }
      else             { a = m[(size_t)row * 256 + (col - 640)]; e = em[col - 640]; }
      s += a * e;
      apack[(size_t)row * 896 + col] = f2bf(a);
    }
    s += __shfl_xor(s, 1);
    s += __shfl_xor(s, 2);
    s += __shfl_xor(s, 4);
    s += __shfl_xor(s, 8);
    s += __shfl_xor(s, 16);
    s += __shfl_xor(s, 32);
    if (lane == 0) uout[row] = s;
  }
}

// ---------------- K2: main GEMM ---------------------------------------------
// grid 512 = 128 M-tiles x 4 N-slices, XCD-clustered; 512 thr; LDS 80KB.
// per 40KB buffer: A [8kb][128r][8] @0, B [8kk][128n][8] @8192 u16,
//                  S [8kk][64n][8] @16384 u16 (chunks 10-13).
__global__ __launch_bounds__(512, 4) void lmu_gemm(
    const u16* __restrict__ ws, const float* __restrict__ BT,
    float* __restrict__ out) {
  __shared__ __align__(16) u16 smem[2 * 20480];
  const int tid  = threadIdx.x;
  const int lane = tid & 63;
  const int w    = tid >> 6;     // 0..7
  const int wr   = w >> 1;       // 0..3 (32-row slice)
  const int wc   = w & 1;        // 0..1 (64-col slice)
  const int lm   = lane & 15;
  const int kg   = lane >> 4;
  const int bid  = blockIdx.x;
  const int mi   = (bid & 7) | ((bid >> 5) << 3);  // same-m N-slices -> same XCD
  const int nsl  = (bid >> 3) & 3;
  const int b0   = mi * 128;

  const u16* apack = ws + APACK;
  const u16* wpk   = ws + WPACK;
  const u16* atp   = ws + ATPACK;

  f32x4 acc[2][4];    // new_h: 2 Mfrag x 4 Nfrag (32r x 64c per wave)
  f32x4 acc2[2][2];   // new_m: 2 Mfrag x 2 Nfrag (32c per wave)
#pragma unroll
  for (int mt = 0; mt < 2; ++mt) {
#pragma unroll
    for (int ct = 0; ct < 4; ++ct) acc[mt][ct] = (f32x4){0.f, 0.f, 0.f, 0.f};
#pragma unroll
    for (int ct = 0; ct < 2; ++ct) acc2[mt][ct] = (f32x4){0.f, 0.f, 0.f, 0.f};
  }

  auto stage = [&](int c) {
    u16* buf = smem + (c & 1) * 20480;
#pragma unroll
    for (int ph = 0; ph < 2; ++ph) {           // A chunk: 16KB
      int i = ph * 512 + tid;
      int kb = i >> 7, r = i & 127;
      gload16(apack + (size_t)(b0 + r) * 896 + c * 64 + kb * 8, buf + i * 8);
    }
#pragma unroll
    for (int ph = 0; ph < 2; ++ph) {           // B chunk: 16KB
      int i = ph * 512 + tid;
      int kk = i >> 7, n = i & 127;
      gload16(wpk + ((size_t)(c * 8 + kk) * 512 + nsl * 128 + n) * 8,
              buf + 8192 + i * 8);
    }
    if (c >= 10) {                              // side B (atpack): 8KB
      int kk = tid >> 6, n = tid & 63;
      gload16(atp + ((size_t)((c - 10) * 8 + kk) * 256 + nsl * 64 + n) * 8,
              buf + 16384 + tid * 8);
    }
  };

  auto mma = [&](int c) {
    const u16* buf = smem + (c & 1) * 20480;
#pragma unroll
    for (int ks = 0; ks < 2; ++ks) {
      const int kq = ks * 4 + kg;
      bf16x8 a[2];
#pragma unroll
      for (int mt = 0; mt < 2; ++mt)
        a[mt] = *(const bf16x8*)(buf + (kq * 128 + wr * 32 + mt * 16 + lm) * 8);
#pragma unroll
      for (int ct = 0; ct < 4; ++ct) {
        bf16x8 b = *(const bf16x8*)(buf + 8192 + (kq * 128 + wc * 64 + ct * 16 + lm) * 8);
#pragma unroll
        for (int mt = 0; mt < 2; ++mt)
          acc[mt][ct] = __builtin_amdgcn_mfma_f32_16x16x32_bf16(a[mt], b, acc[mt][ct], 0, 0, 0);
      }
      if (c >= 10) {
#pragma unroll
        for (int ct = 0; ct < 2; ++ct) {
          bf16x8 b = *(const bf16x8*)(buf + 16384 + (kq * 64 + wc * 32 + ct * 16 + lm) * 8);
#pragma unroll
          for (int mt = 0; mt < 2; ++mt)
            acc2[mt][ct] = __builtin_amdgcn_mfma_f32_16x16x32_bf16(a[mt], b, acc2[mt][ct], 0, 0, 0);
        }
      }
    }
  };

  stage(0);
  __syncthreads();
#pragma unroll
  for (int c = 0; c < 14; ++c) {
    if (c < 13) stage(c + 1);   // issue next-chunk loads first (T3)
    mma(c);                     // compute current from LDS
    __syncthreads();            // drains vmcnt -> next buffer ready
  }

  // ---- epilogue ----
  const float* uf  = (const float*)(ws + UOFF);
  const float* wuf = (const float*)(ws + WUOFF);
  float wuv[4], btv[2];
#pragma unroll
  for (int ct = 0; ct < 4; ++ct) wuv[ct] = wuf[nsl * 128 + wc * 64 + ct * 16 + lm];
#pragma unroll
  for (int ct = 0; ct < 2; ++ct) btv[ct] = BT[nsl * 64 + wc * 32 + ct * 16 + lm];
  float* outm = out + (size_t)BATCH * 512;
#pragma unroll
  for (int mt = 0; mt < 2; ++mt)
#pragma unroll
    for (int j = 0; j < 4; ++j) {
      int rl = wr * 32 + mt * 16 + kg * 4 + j;
      size_t row = (size_t)(b0 + rl);
      float uv = uf[row];
#pragma unroll
      for (int ct = 0; ct < 4; ++ct) {
        float v = acc[mt][ct][j] + uv * wuv[ct];
        out[row * 512 + nsl * 128 + wc * 64 + ct * 16 + lm] = 1.0f / (1.0f + __expf(-v));
      }
#pragma unroll
      for (int ct = 0; ct < 2; ++ct)
        outm[row * 256 + nsl * 64 + wc * 32 + ct * 16 + lm] = acc2[mt][ct][j] + uv * btv[ct];
    }
}

extern "C" void kernel_launch(void* const* d_in, const int* in_sizes, int n_in,
                              void* d_out, int out_size, void* d_ws, size_t ws_size,
                              hipStream_t stream) {
  const float* x  = (const float*)d_in[0];
  const float* h  = (const float*)d_in[1];
  const float* m  = (const float*)d_in[2];
  const float* Wx = (const float*)d_in[3];
  const float* Wh = (const float*)d_in[4];
  const float* Wm = (const float*)d_in[5];
  const float* ex = (const float*)d_in[6];
  const float* eh = (const float*)d_in[7];
  const float* em = (const float*)d_in[8];
  const float* AT = (const float*)d_in[9];
  const float* BT = (const float*)d_in[10];
  float* out = (float*)d_out;
  u16* ws = (u16*)d_ws;   // uses ~30.5 MB

  lmu_pack<<<(PACK_ITEMS + 255) / 256, 256, 0, stream>>>(Wx, Wh, Wm, AT, BT, ws);
  lmu_wm2<<<dim3(32, 4), 256, 0, stream>>>(Wm, AT, ws);
  lmu_prep<<<1024, 256, 0, stream>>>(x, h, m, ex, eh, em, ws);
  lmu_gemm<<<512, 512, 0, stream>>>(ws, BT, out);
}